// Round 11
// baseline (6710.888 us; speedup 1.0000x reference)
//
#include <hip/hip_runtime.h>
#include <stdint.h>

#define HH 256
#define SS 2048
#define BB 256
#define DD 64
#define CHS 32
#define RING 8

typedef __attribute__((ext_vector_type(8))) short bh8;
typedef __attribute__((ext_vector_type(4))) float fx4;
typedef __attribute__((ext_vector_type(4))) float f4v;

// ---------------- ws layout (bytes) ----------------
#define L0TAG_OFF 0ull
#define L1TAG_OFF 2048ull
#define P0TAG_OFF 4096ull
#define P1TAG_OFF 8192ull
#define BF0_OFF   12288ull
#define BF1_OFF   16384ull
#define FIN_OFF   20480ull
#define WBF0_OFF  524288ull
#define WBF1_OFF  1048576ull
#define YS_OFF    2097152ull
#define XP0_OFF   37748736ull
#define XP1_OFF   139460608ull
#define WS_NEED   (XP1_OFF + 100663296ull)

__device__ __forceinline__ short f2bf(float f) {
  uint32_t u = __builtin_bit_cast(uint32_t, f);
  u += 0x7FFFu + ((u >> 16) & 1u);
  return (short)(u >> 16);
}
__device__ __forceinline__ float bf2f(short s) {
  uint32_t u = ((uint32_t)(uint16_t)s) << 16;
  return __builtin_bit_cast(float, u);
}
__device__ __forceinline__ float lof(int u) {
  return __builtin_bit_cast(float, (uint32_t)u << 16);
}
__device__ __forceinline__ float hif(int u) {
  return __builtin_bit_cast(float, (uint32_t)u & 0xFFFF0000u);
}
__device__ __forceinline__ uint32_t pack2(float a, float b) {
  return ((uint32_t)(uint16_t)f2bf(a)) | (((uint32_t)(uint16_t)f2bf(b)) << 16);
}
__device__ __forceinline__ float rcp_(float x) { return __builtin_amdgcn_rcpf(x); }
__device__ __forceinline__ float tanh_(float x) {
  x = fminf(fmaxf(x, -15.f), 15.f);
  float e = __expf(2.0f * x);
  return (e - 1.0f) / (e + 1.0f);
}
__device__ __forceinline__ fx4 mfma16(bh8 a, bh8 b, fx4 c) {
  return __builtin_amdgcn_mfma_f32_16x16x32_bf16(a, b, c, 0, 0, 0);
}
__device__ __forceinline__ bh8 cvt8(f4v a, f4v b) {
  bh8 r;
  r[0]=f2bf(a[0]); r[1]=f2bf(a[1]); r[2]=f2bf(a[2]); r[3]=f2bf(a[3]);
  r[4]=f2bf(b[0]); r[5]=f2bf(b[1]); r[6]=f2bf(b[2]); r[7]=f2bf(b[3]);
  return r;
}
__device__ __forceinline__ bh8 gld16_cc(const short* p) {
  bh8 r; asm volatile("global_load_dwordx4 %0, %1, off sc0 sc1" : "=v"(r) : "v"(p));
  return r;
}
__device__ __forceinline__ void stw_cc(uint32_t* p, uint32_t v) {
  asm volatile("global_store_dword %0, %1, off sc0 sc1" :: "v"(p), "v"(v) : "memory");
}
__device__ __forceinline__ void vwait0() {
  asm volatile("s_waitcnt vmcnt(0)" ::: "memory");
  __builtin_amdgcn_sched_barrier(0);
}
template<int SLP>
__device__ __forceinline__ void wait_nz_cc(const uint32_t* p) {
  for (;;) {
    uint32_t v;
    asm volatile("global_load_dword %0, %1, off sc0 sc1" : "=v"(v) : "v"(p));
    asm volatile("s_waitcnt vmcnt(0)" ::: "memory");
    if (v != 0u) break;
    __builtin_amdgcn_s_sleep(SLP);
  }
  __builtin_amdgcn_sched_barrier(0);
}
template<int SLP>
__device__ __forceinline__ void wait_ge_cc(const uint32_t* p, uint32_t need) {
  for (;;) {
    uint32_t v;
    asm volatile("global_load_dword %0, %1, off sc0 sc1" : "=v"(v) : "v"(p));
    asm volatile("s_waitcnt vmcnt(0)" ::: "memory");
    if (v >= need) break;
    __builtin_amdgcn_s_sleep(SLP);
  }
  __builtin_amdgcn_sched_barrier(0);
}

// issue 6 xp loads (R,Z,N for 2 col-tiles of wave w) for step T into named regs
#define ISSUE_XP(T, rA,rB,rC,rD,rE,rF) \
  { const short* b_ = xp + ((size_t)(((((T) >> 5) & 7))*16 + g)*32 + ((T) & 31))*12288 + w*1536 + l*4; \
    asm volatile("global_load_dwordx2 %0, %1, off sc0 sc1"             : "=v"(rA) : "v"(b_)); \
    asm volatile("global_load_dwordx2 %0, %1, off offset:512 sc0 sc1"  : "=v"(rB) : "v"(b_)); \
    asm volatile("global_load_dwordx2 %0, %1, off offset:1024 sc0 sc1" : "=v"(rC) : "v"(b_)); \
    asm volatile("global_load_dwordx2 %0, %1, off offset:1536 sc0 sc1" : "=v"(rD) : "v"(b_)); \
    asm volatile("global_load_dwordx2 %0, %1, off offset:2048 sc0 sc1" : "=v"(rE) : "v"(b_)); \
    asm volatile("global_load_dwordx2 %0, %1, off offset:2560 sc0 sc1" : "=v"(rF) : "v"(b_)); }

// MFMA over K=256 for one column-tile (all 3 gate weight sets in registers)
#define CTL_MFMA(CTL, accR, accZ, accN) \
  _Pragma("unroll") \
  for (int kf = 0; kf < 8; ++kf) { \
    accR = mfma16(af[kf], whhF[CTL][0][kf], accR); \
    accZ = mfma16(af[kf], whhF[CTL][1][kf], accZ); \
    accN = mfma16(af[kf], whhF[CTL][2][kf], accN); \
  }

#define CTL_GATES(CTL, accR, accZ, accN, X0,X1,X2,X3, BHN) \
  _Pragma("unroll") \
  for (int i = 0; i < 4; ++i) { \
    float xnv = (i==0)?(X0):((i==1)?(X1):((i==2)?(X2):(X3))); \
    float r = rcp_(1.0f + __expf(-accR[i])); \
    float z = rcp_(1.0f + __expf(-accZ[i])); \
    float na = xnv + r * (accN[i] + (BHN)); \
    float n = 1.0f - 2.0f * rcp_(__expf(2.0f*na) + 1.0f); \
    float h = n + z * (hp[(CTL)*4+i] - n); \
    hp[(CTL)*4+i] = h; \
    int la = lg*4 + i + 16*((CTL)*2 + b3); \
    pubp[wb + la*8 + j7] = f2bf(h); \
  }

// One recurrent step. ISEVEN=1 (pair top): full drain-0 covers BOTH register
// sets (issued 1.0-2.0 steps earlier). ISEVEN=0 (odd): no wait needed — its
// set was drained at the pair top. No counted vmcnt anywhere: robust to any
// compiler-generated VMEM (the round-9/10 failure mode).
#define REC_STEP2(T, rA,rB,rC,rD,rE,rF, ISEVEN) \
  { \
    if (ISEVEN) { \
      asm volatile("s_waitcnt vmcnt(0)" ::: "memory"); \
      __builtin_amdgcn_sched_barrier(0); \
    } \
    const int t_ = (T); \
    const int buf = t_ & 1; \
    const int rb = (buf ^ 1) * 4096; \
    const int wb = buf * 4096 + w * 512; \
    fx4 aR0, aZ0, aR1, aZ1; \
    fx4 aN0 = {0.f,0.f,0.f,0.f}, aN1 = {0.f,0.f,0.f,0.f}; \
    aR0[0]=lof(rA.x); aR0[1]=hif(rA.x); aR0[2]=lof(rA.y); aR0[3]=hif(rA.y); \
    aZ0[0]=lof(rB.x); aZ0[1]=hif(rB.x); aZ0[2]=lof(rB.y); aZ0[3]=hif(rB.y); \
    float x0=lof(rC.x), x1=hif(rC.x), x2=lof(rC.y), x3=hif(rC.y); \
    aR1[0]=lof(rD.x); aR1[1]=hif(rD.x); aR1[2]=lof(rD.y); aR1[3]=hif(rD.y); \
    aZ1[0]=lof(rE.x); aZ1[1]=hif(rE.x); aZ1[2]=lof(rE.y); aZ1[3]=hif(rE.y); \
    float x4=lof(rF.x), x5=hif(rF.x), x6=lof(rF.y), x7=hif(rF.y); \
    const int tn2_ = t_ + 2; \
    if (tn2_ < SS) { \
      if (ISEVEN && (tn2_ & (CHS-1)) == 0) { \
        wait_nz_cc<2>(ptag + (tn2_ >> 5)); \
        if (LAYER == 0 && (tn2_ >> 5) >= RING) \
          wait_nz_cc<2>(bptag + ((tn2_ >> 5) - RING)); \
      } \
      ISSUE_XP(tn2_, rA,rB,rC,rD,rE,rF); \
    } \
    bh8 af[8]; \
    _Pragma("unroll") \
    for (int kf = 0; kf < 8; ++kf) af[kf] = *(const bh8*)&pubp[rb + kf*512 + l*8]; \
    CTL_MFMA(0, aR0, aZ0, aN0) \
    CTL_GATES(0, aR0, aZ0, aN0, x0,x1,x2,x3, bhN0) \
    CTL_MFMA(1, aR1, aZ1, aN1) \
    CTL_GATES(1, aR1, aZ1, aN1, x4,x5,x6,x7, bhN1) \
    if (LAYER == 0) { \
      bh8 mf = *(const bh8*)&pubp[wb + l*8]; \
      short* dst = ys + ((size_t)(((t_ >> 5) & 7)*16 + g)*32 + (t_ & 31))*4096 + w*512 + l*8; \
      asm volatile("global_store_dwordx4 %0, %1, off sc0 sc1" :: "v"(dst), "v"(mf) : "memory"); \
    } \
    __syncthreads(); \
    if (!ISEVEN) { \
      const int tn_ = t_ + 1; \
      if ((tn_ & (CHS-1)) == 0) { \
        asm volatile("s_waitcnt vmcnt(0)" ::: "memory"); \
        __syncthreads(); \
        if (tid == 0) stw_cc(mytag, (uint32_t)tn_); \
      } \
    } \
  }

// ---------------- recurrent block: one (layer, 16-row group) per CU ----------
template<int LAYER>
__device__ __forceinline__ void run_rec(
    const float* __restrict__ Whh, const float* __restrict__ bhh,
    uint8_t* __restrict__ ws, int g, short* pubp)
{
  const int tid = threadIdx.x;
  const int w = tid >> 6, l = tid & 63;
  const int l15 = l & 15, lg = l >> 4;
  const int b3 = l15 >> 3, j7 = l & 7;

  for (int i = tid; i < 8192; i += 512) pubp[i] = 0;

  bh8 whhF[2][3][8];
#pragma unroll
  for (int ctl = 0; ctl < 2; ++ctl) {
    const int col = (2*w + ctl)*16 + l15;
#pragma unroll
    for (int gate = 0; gate < 3; ++gate) {
      const float* base = Whh + (size_t)(gate*HH + col)*HH;
#pragma unroll
      for (int kf = 0; kf < 8; ++kf) {
        const float* p = base + kf*32 + lg*8;
        whhF[ctl][gate][kf] = cvt8(*(const f4v*)p, *(const f4v*)(p + 4));
      }
    }
  }
#pragma unroll
  for (int ctl = 0; ctl < 2; ++ctl)
#pragma unroll
    for (int gate = 0; gate < 3; ++gate)
#pragma unroll
      for (int kf = 0; kf < 8; ++kf)
        asm volatile("" : "+v"(whhF[ctl][gate][kf]));

  const float bhN0 = bhh[2*HH + (2*w + 0)*16 + l15];
  const float bhN1 = bhh[2*HH + (2*w + 1)*16 + l15];

  uint32_t* mytag       = (uint32_t*)(ws + (LAYER ? L1TAG_OFF : L0TAG_OFF) + (size_t)g*128);
  const uint32_t* ptag  = (const uint32_t*)(ws + (LAYER ? P1TAG_OFF : P0TAG_OFF)) + g*64;
  const uint32_t* bptag = (const uint32_t*)(ws + P1TAG_OFF) + g*64;
  short* xp  = (short*)(ws + (LAYER ? XP1_OFF : XP0_OFF));
  short* ys  = (short*)(ws + YS_OFF);
  short* fin = (short*)(ws + FIN_OFF);

  __syncthreads();   // pubp zero visible

  wait_nz_cc<1>(ptag);
  int2 xA0,xB0,xC0,xD0,xE0,xF0, xA1,xB1,xC1,xD1,xE1,xF1;
  ISSUE_XP(0, xA0,xB0,xC0,xD0,xE0,xF0);
  ISSUE_XP(1, xA1,xB1,xC1,xD1,xE1,xF1);

  float hp[8] = {0,0,0,0,0,0,0,0};

  for (int tp = 0; tp < SS; tp += 2) {
    REC_STEP2(tp,     xA0,xB0,xC0,xD0,xE0,xF0, 1)
    REC_STEP2(tp + 1, xA1,xB1,xC1,xD1,xE1,xF1, 0)
  }

  // final h frags for out-projection (t=2047 -> buf 1)
  bh8 mf = *(const bh8*)&pubp[4096 + w*512 + l*8];
  short* dst = fin + ((size_t)(LAYER*16 + g)*8 + w)*512 + l*8;
  asm volatile("global_store_dwordx4 %0, %1, off sc0 sc1" :: "v"(dst), "v"(mf) : "memory");
  asm volatile("s_waitcnt vmcnt(0)" ::: "memory");
}

// ---------------- proj0: xp0[t] = x[t]*Wih0^T + bias (K=64) ----------------
__device__ __forceinline__ void run_proj0(const float* __restrict__ x,
                                          uint8_t* __restrict__ ws, int g, int c)
{
  const int tid = threadIdx.x, w = tid >> 6, l = tid & 63, l15 = l & 15, lg = l >> 4;
  if (c >= RING)
    wait_ge_cc<3>((const uint32_t*)(ws + L0TAG_OFF + (size_t)g*128), (uint32_t)(CHS*(c - RING + 1)));
  bh8 A[4][2];
#pragma unroll
  for (int tt = 0; tt < 4; ++tt) {
    const int t = c*32 + w*4 + tt;
#pragma unroll
    for (int kf = 0; kf < 2; ++kf) {
      const float* p = x + ((size_t)t*BB + g*16 + l15)*DD + kf*32 + lg*8;
      A[tt][kf] = cvt8(*(const f4v*)p, *(const f4v*)(p + 4));
    }
  }
  const bh8* WB = (const bh8*)(ws + WBF0_OFF);
  const float* BF = (const float*)(ws + BF0_OFF);
  short* xp0 = (short*)(ws + XP0_OFF);
  const size_t obase = ((size_t)((c & 7)*16 + g)*32 + w*4)*12288 + l*4;
  for (int ct = 0; ct < 48; ++ct) {
    bh8 B0 = WB[(size_t)(ct*2 + 0)*64 + l];
    bh8 B1 = WB[(size_t)(ct*2 + 1)*64 + l];
    const float bb = BF[(ct >> 4)*256 + (ct & 15)*16 + l15];
    const int fid = (ct & 15)*3 + (ct >> 4);
#pragma unroll
    for (int tt = 0; tt < 4; ++tt) {
      fx4 acc = {0.f, 0.f, 0.f, 0.f};
      acc = mfma16(A[tt][0], B0, acc);
      acc = mfma16(A[tt][1], B1, acc);
      int2 v;
      v.x = (int)pack2(acc[0] + bb, acc[1] + bb);
      v.y = (int)pack2(acc[2] + bb, acc[3] + bb);
      short* dst = xp0 + obase + (size_t)tt*12288 + fid*256;
      asm volatile("global_store_dwordx2 %0, %1, off sc0 sc1" :: "v"(dst), "v"(v) : "memory");
    }
  }
  asm volatile("s_waitcnt vmcnt(0)" ::: "memory");
  __syncthreads();
  if (tid == 0) stw_cc((uint32_t*)(ws + P0TAG_OFF) + g*64 + c, 1u);
}

// ---------------- proj1: xp1[t] = ys0[t]*Wih1^T + bias (K=256) --------------
__device__ __forceinline__ void run_proj1(uint8_t* __restrict__ ws, int g, int c)
{
  const int tid = threadIdx.x, w = tid >> 6, l = tid & 63, l15 = l & 15;
  wait_ge_cc<3>((const uint32_t*)(ws + L0TAG_OFF + (size_t)g*128), (uint32_t)(CHS*(c + 1)));
  if (c >= RING)
    wait_ge_cc<3>((const uint32_t*)(ws + L1TAG_OFF + (size_t)g*128), (uint32_t)(CHS*(c - RING + 1)));
  const short* ys = (const short*)(ws + YS_OFF) + ((size_t)((c & 7)*16 + g)*32)*4096;
  bh8 A[4][8];
#pragma unroll
  for (int tt = 0; tt < 4; ++tt)
#pragma unroll
    for (int kf = 0; kf < 8; ++kf)
      A[tt][kf] = gld16_cc(ys + (size_t)(w*4 + tt)*4096 + kf*512 + l*8);
  asm volatile("s_waitcnt vmcnt(0)" ::: "memory");
  __builtin_amdgcn_sched_barrier(0);
  const bh8* WB = (const bh8*)(ws + WBF1_OFF);
  const float* BF = (const float*)(ws + BF1_OFF);
  short* xp1 = (short*)(ws + XP1_OFF);
  const size_t obase = ((size_t)((c & 7)*16 + g)*32 + w*4)*12288 + l*4;
  for (int ct = 0; ct < 48; ++ct) {
    bh8 B[8];
#pragma unroll
    for (int kf = 0; kf < 8; ++kf) B[kf] = WB[(size_t)(ct*8 + kf)*64 + l];
    const float bb = BF[(ct >> 4)*256 + (ct & 15)*16 + l15];
    const int fid = (ct & 15)*3 + (ct >> 4);
#pragma unroll
    for (int tt = 0; tt < 4; ++tt) {
      fx4 acc = {0.f, 0.f, 0.f, 0.f};
#pragma unroll
      for (int kf = 0; kf < 8; ++kf) acc = mfma16(A[tt][kf], B[kf], acc);
      int2 v;
      v.x = (int)pack2(acc[0] + bb, acc[1] + bb);
      v.y = (int)pack2(acc[2] + bb, acc[3] + bb);
      short* dst = xp1 + obase + (size_t)tt*12288 + fid*256;
      asm volatile("global_store_dwordx2 %0, %1, off sc0 sc1" :: "v"(dst), "v"(v) : "memory");
    }
  }
  asm volatile("s_waitcnt vmcnt(0)" ::: "memory");
  __syncthreads();
  if (tid == 0) stw_cc((uint32_t*)(ws + P1TAG_OFF) + g*64 + c, 1u);
}

// ---------------- kernels ----------------
__global__ __launch_bounds__(512) void gru_prep(
    const float* __restrict__ Wih0, const float* __restrict__ Wih1,
    const float* __restrict__ bih0, const float* __restrict__ bhh0,
    const float* __restrict__ bih1, const float* __restrict__ bhh1,
    uint8_t* __restrict__ ws)
{
  const int bid = blockIdx.x, tid = threadIdx.x;
  if (bid == 60) {
    float* BF0 = (float*)(ws + BF0_OFF);
    float* BF1 = (float*)(ws + BF1_OFF);
    for (int i = tid; i < 768; i += 512) {
      const int gate = i >> 8;
      BF0[i] = bih0[i] + (gate < 2 ? bhh0[i] : 0.f);
      BF1[i] = bih1[i] + (gate < 2 ? bhh1[i] : 0.f);
    }
    return;
  }
  const int W = bid*8 + (tid >> 6), l = tid & 63, l15 = l & 15, lg = l >> 4;
  if (W < 96) {
    const int ct = W >> 1, kf = W & 1;
    const float* p = Wih0 + (size_t)(ct*16 + l15)*DD + kf*32 + lg*8;
    ((bh8*)(ws + WBF0_OFF))[(size_t)W*64 + l] = cvt8(*(const f4v*)p, *(const f4v*)(p + 4));
  } else {
    const int V = W - 96, ct = V >> 3, kf = V & 7;
    const float* p = Wih1 + (size_t)(ct*16 + l15)*HH + kf*32 + lg*8;
    ((bh8*)(ws + WBF1_OFF))[(size_t)V*64 + l] = cvt8(*(const f4v*)p, *(const f4v*)(p + 4));
  }
}

__global__ __launch_bounds__(512)
__attribute__((amdgpu_waves_per_eu(2, 2)))
void gru_mega(
    const float* __restrict__ x,
    const float* __restrict__ Whh0, const float* __restrict__ bhh0,
    const float* __restrict__ Whh1, const float* __restrict__ bhh1,
    uint8_t* __restrict__ ws)
{
  __shared__ short pubp[8192];   // [2 buf][8 kf][64 lane][8] h exchange
  const int bid = blockIdx.x;
  if (bid < 16)      run_rec<0>(Whh0, bhh0, ws, bid, pubp);
  else if (bid < 32) run_rec<1>(Whh1, bhh1, ws, bid - 16, pubp);
  else {
    const int j = bid - 32, c = j >> 5, r = j & 31;
    if (r < 16) run_proj0(x, ws, r, c);
    else        run_proj1(ws, r - 16, c);
  }
}

__global__ __launch_bounds__(512) void gru_out(
    const uint8_t* __restrict__ ws,
    const float* __restrict__ Wout, const float* __restrict__ bout,
    float* __restrict__ out)
{
  const short* fin = (const short*)(ws + FIN_OFF);
  const int bid = blockIdx.x;
  const int layer = bid >> 4, g = bid & 15;
  const int tid = threadIdx.x;
  const int row = tid >> 5, o = tid & 31;
  const short* src = fin + (size_t)(layer*16 + g)*4096;
  float acc = 0.f;
#pragma unroll 8
  for (int h = 0; h < HH; ++h) {
    const int f = h >> 5, lane = row + ((h & 31) >> 3)*16, idx = h & 7;
    acc += bf2f(src[f*512 + lane*8 + idx]) * Wout[o*HH + h];
  }
  out[((size_t)(layer*BB) + g*16 + row)*32 + o] = tanh_(acc + bout[o]);
}

extern "C" void kernel_launch(void* const* d_in, const int* in_sizes, int n_in,
                              void* d_out, int out_size, void* d_ws, size_t ws_size,
                              hipStream_t stream) {
  const float* x    = (const float*)d_in[0];
  const float* Wih0 = (const float*)d_in[1];
  const float* Whh0 = (const float*)d_in[2];
  const float* bih0 = (const float*)d_in[3];
  const float* bhh0 = (const float*)d_in[4];
  const float* Wih1 = (const float*)d_in[5];
  const float* Whh1 = (const float*)d_in[6];
  const float* bih1 = (const float*)d_in[7];
  const float* bhh1 = (const float*)d_in[8];
  const float* Wout = (const float*)d_in[9];
  const float* bout = (const float*)d_in[10];
  uint8_t* ws = (uint8_t*)d_ws;

  if (ws_size < WS_NEED) return;

  (void)hipMemsetAsync(ws, 0, 16384, stream);
  gru_prep<<<dim3(61), dim3(512), 0, stream>>>(Wih0, Wih1, bih0, bhh0, bih1, bhh1, ws);
  gru_mega<<<dim3(2080), dim3(512), 0, stream>>>(x, Whh0, bhh0, Whh1, bhh1, ws);
  gru_out<<<dim3(32), dim3(512), 0, stream>>>(ws, Wout, bout, (float*)d_out);
}

// Round 14
// 5700.579 us; speedup vs baseline: 1.1772x; 1.1772x over previous
//
#include <hip/hip_runtime.h>
#include <stdint.h>

#define HH 256
#define SS 2048
#define BB 256
#define DD 64
#define CHS 32
#define RING 8

typedef __attribute__((ext_vector_type(8))) short bh8;
typedef __attribute__((ext_vector_type(4))) float fx4;
typedef __attribute__((ext_vector_type(4))) float f4v;

// ---------------- ws layout (bytes) ----------------
#define L0TAG_OFF 0ull
#define L1TAG_OFF 2048ull
#define P0TAG_OFF 4096ull
#define P1TAG_OFF 8192ull
#define BF0_OFF   12288ull
#define BF1_OFF   16384ull
#define FIN_OFF   20480ull
#define WBF0_OFF  524288ull
#define WBF1_OFF  1048576ull
#define YS_OFF    2097152ull
#define XP0_OFF   37748736ull
#define XP1_OFF   139460608ull
#define WS_NEED   (XP1_OFF + 100663296ull)

__device__ __forceinline__ short f2bf(float f) {
  uint32_t u = __builtin_bit_cast(uint32_t, f);
  u += 0x7FFFu + ((u >> 16) & 1u);
  return (short)(u >> 16);
}
__device__ __forceinline__ float bf2f(short s) {
  uint32_t u = ((uint32_t)(uint16_t)s) << 16;
  return __builtin_bit_cast(float, u);
}
__device__ __forceinline__ float lof(int u) {
  return __builtin_bit_cast(float, (uint32_t)u << 16);
}
__device__ __forceinline__ float hif(int u) {
  return __builtin_bit_cast(float, (uint32_t)u & 0xFFFF0000u);
}
__device__ __forceinline__ uint32_t pack2(float a, float b) {
  return ((uint32_t)(uint16_t)f2bf(a)) | (((uint32_t)(uint16_t)f2bf(b)) << 16);
}
__device__ __forceinline__ float rcp_(float x) { return __builtin_amdgcn_rcpf(x); }
__device__ __forceinline__ float tanh_(float x) {
  x = fminf(fmaxf(x, -15.f), 15.f);
  float e = __expf(2.0f * x);
  return (e - 1.0f) / (e + 1.0f);
}
__device__ __forceinline__ fx4 mfma16(bh8 a, bh8 b, fx4 c) {
  return __builtin_amdgcn_mfma_f32_16x16x32_bf16(a, b, c, 0, 0, 0);
}
__device__ __forceinline__ bh8 cvt8(f4v a, f4v b) {
  bh8 r;
  r[0]=f2bf(a[0]); r[1]=f2bf(a[1]); r[2]=f2bf(a[2]); r[3]=f2bf(a[3]);
  r[4]=f2bf(b[0]); r[5]=f2bf(b[1]); r[6]=f2bf(b[2]); r[7]=f2bf(b[3]);
  return r;
}
__device__ __forceinline__ bh8 gld16_cc(const short* p) {
  bh8 r; asm volatile("global_load_dwordx4 %0, %1, off sc0 sc1" : "=v"(r) : "v"(p));
  return r;
}
__device__ __forceinline__ void stw_cc(uint32_t* p, uint32_t v) {
  asm volatile("global_store_dword %0, %1, off sc0 sc1" :: "v"(p), "v"(v) : "memory");
}
__device__ __forceinline__ void vwait0() {
  asm volatile("s_waitcnt vmcnt(0)" ::: "memory");
  __builtin_amdgcn_sched_barrier(0);
}
__device__ __forceinline__ void vwait1() {
  asm volatile("s_waitcnt vmcnt(1)" ::: "memory");
  __builtin_amdgcn_sched_barrier(0);
}
template<int SLP>
__device__ __forceinline__ void wait_nz_cc(const uint32_t* p) {
  for (;;) {
    uint32_t v;
    asm volatile("global_load_dword %0, %1, off sc0 sc1" : "=v"(v) : "v"(p));
    asm volatile("s_waitcnt vmcnt(0)" ::: "memory");
    if (v != 0u) break;
    __builtin_amdgcn_s_sleep(SLP);
  }
  __builtin_amdgcn_sched_barrier(0);
}
template<int SLP>
__device__ __forceinline__ void wait_ge_cc(const uint32_t* p, uint32_t need) {
  for (;;) {
    uint32_t v;
    asm volatile("global_load_dword %0, %1, off sc0 sc1" : "=v"(v) : "v"(p));
    asm volatile("s_waitcnt vmcnt(0)" ::: "memory");
    if (v >= need) break;
    __builtin_amdgcn_s_sleep(SLP);
  }
  __builtin_amdgcn_sched_barrier(0);
}

// issue 6 xp loads (R,Z,N for 2 col-tiles of wave w) for step T
#define ISSUE_XP(T) \
  { const short* b_ = xp + ((size_t)(((((T) >> 5) & 7))*16 + g)*32 + ((T) & 31))*12288 + w*1536 + l*4; \
    asm volatile("global_load_dwordx2 %0, %1, off sc0 sc1"             : "=v"(xA) : "v"(b_)); \
    asm volatile("global_load_dwordx2 %0, %1, off offset:512 sc0 sc1"  : "=v"(xB) : "v"(b_)); \
    asm volatile("global_load_dwordx2 %0, %1, off offset:1024 sc0 sc1" : "=v"(xC) : "v"(b_)); \
    asm volatile("global_load_dwordx2 %0, %1, off offset:1536 sc0 sc1" : "=v"(xD) : "v"(b_)); \
    asm volatile("global_load_dwordx2 %0, %1, off offset:2048 sc0 sc1" : "=v"(xE) : "v"(b_)); \
    asm volatile("global_load_dwordx2 %0, %1, off offset:2560 sc0 sc1" : "=v"(xF) : "v"(b_)); }

// MFMA over K=256 for one column-tile (all 3 gate weight sets in registers)
#define CTL_MFMA(CTL, accR, accZ, accN) \
  _Pragma("unroll") \
  for (int kf = 0; kf < 8; ++kf) { \
    accR = mfma16(af[kf], whhF[CTL][0][kf], accR); \
    accZ = mfma16(af[kf], whhF[CTL][1][kf], accZ); \
    accN = mfma16(af[kf], whhF[CTL][2][kf], accN); \
  }

#define CTL_GATES(CTL, accR, accZ, accN, X0,X1,X2,X3, BHN) \
  _Pragma("unroll") \
  for (int i = 0; i < 4; ++i) { \
    float xnv = (i==0)?(X0):((i==1)?(X1):((i==2)?(X2):(X3))); \
    float r = rcp_(1.0f + __expf(-accR[i])); \
    float z = rcp_(1.0f + __expf(-accZ[i])); \
    float na = xnv + r * (accN[i] + (BHN)); \
    float n = 1.0f - 2.0f * rcp_(__expf(2.0f*na) + 1.0f); \
    float h = n + z * (hp[(CTL)*4+i] - n); \
    hp[(CTL)*4+i] = h; \
    int la = lg*4 + i + 16*((CTL)*2 + b3); \
    pubp[wb + la*8 + j7] = f2bf(h); \
  }

// One step, round-8 wait discipline (vwait1/vwait0 only — robust to compiler
// VMEM), but xp(t+1) issued EARLY: right after the unpack frees xA..xF, so
// the loads overlap this step's 48 MFMAs + gates instead of ~one barrier.
#define REC_STEP(T) \
  { \
    const int t_ = (T); \
    if (LAYER == 0 && (t_ & (CHS-1)) != 0) vwait1(); else vwait0(); \
    const int buf = t_ & 1; \
    const int rb = (buf ^ 1) * 4096; \
    const int wb = buf * 4096 + w * 512; \
    fx4 aR0, aZ0, aR1, aZ1; \
    fx4 aN0 = {0.f,0.f,0.f,0.f}, aN1 = {0.f,0.f,0.f,0.f}; \
    aR0[0]=lof(xA.x); aR0[1]=hif(xA.x); aR0[2]=lof(xA.y); aR0[3]=hif(xA.y); \
    aZ0[0]=lof(xB.x); aZ0[1]=hif(xB.x); aZ0[2]=lof(xB.y); aZ0[3]=hif(xB.y); \
    float x0=lof(xC.x), x1=hif(xC.x), x2=lof(xC.y), x3=hif(xC.y); \
    aR1[0]=lof(xD.x); aR1[1]=hif(xD.x); aR1[2]=lof(xD.y); aR1[3]=hif(xD.y); \
    aZ1[0]=lof(xE.x); aZ1[1]=hif(xE.x); aZ1[2]=lof(xE.y); aZ1[3]=hif(xE.y); \
    float x4=lof(xF.x), x5=hif(xF.x), x6=lof(xF.y), x7=hif(xF.y); \
    const int tn_ = t_ + 1; \
    if (tn_ < SS) { \
      if ((tn_ & (CHS-1)) == 0) { \
        wait_nz_cc<2>(ptag + (tn_ >> 5)); \
        if (LAYER == 0 && (tn_ >> 5) >= RING) \
          wait_nz_cc<2>(bptag + ((tn_ >> 5) - RING)); \
      } \
      ISSUE_XP(tn_); \
    } \
    bh8 af[8]; \
    _Pragma("unroll") \
    for (int kf = 0; kf < 8; ++kf) af[kf] = *(const bh8*)&pubp[rb + kf*512 + l*8]; \
    CTL_MFMA(0, aR0, aZ0, aN0) \
    CTL_GATES(0, aR0, aZ0, aN0, x0,x1,x2,x3, bhN0) \
    CTL_MFMA(1, aR1, aZ1, aN1) \
    CTL_GATES(1, aR1, aZ1, aN1, x4,x5,x6,x7, bhN1) \
    if (LAYER == 0) { \
      bh8 mf = *(const bh8*)&pubp[wb + l*8]; \
      short* dst = ys + ((size_t)(((t_ >> 5) & 7)*16 + g)*32 + (t_ & 31))*4096 + w*512 + l*8; \
      asm volatile("global_store_dwordx4 %0, %1, off sc0 sc1" :: "v"(dst), "v"(mf) : "memory"); \
    } \
    __syncthreads(); \
    if ((tn_ & (CHS-1)) == 0) { \
      asm volatile("s_waitcnt vmcnt(0)" ::: "memory"); \
      __syncthreads(); \
      if (tid == 0) stw_cc(mytag, (uint32_t)tn_); \
    } \
  }

// ---------------- recurrent block: one (layer, 16-row group) per CU ----------
template<int LAYER>
__device__ __forceinline__ void run_rec(
    const float* __restrict__ Whh, const float* __restrict__ bhh,
    uint8_t* __restrict__ ws, int g, short* pubp)
{
  const int tid = threadIdx.x;
  const int w = tid >> 6, l = tid & 63;
  const int l15 = l & 15, lg = l >> 4;
  const int b3 = l15 >> 3, j7 = l & 7;

  for (int i = tid; i < 8192; i += 512) pubp[i] = 0;

  bh8 whhF[2][3][8];
#pragma unroll
  for (int ctl = 0; ctl < 2; ++ctl) {
    const int col = (2*w + ctl)*16 + l15;
#pragma unroll
    for (int gate = 0; gate < 3; ++gate) {
      const float* base = Whh + (size_t)(gate*HH + col)*HH;
#pragma unroll
      for (int kf = 0; kf < 8; ++kf) {
        const float* p = base + kf*32 + lg*8;
        whhF[ctl][gate][kf] = cvt8(*(const f4v*)p, *(const f4v*)(p + 4));
      }
    }
  }
#pragma unroll
  for (int ctl = 0; ctl < 2; ++ctl)
#pragma unroll
    for (int gate = 0; gate < 3; ++gate)
#pragma unroll
      for (int kf = 0; kf < 8; ++kf)
        asm volatile("" : "+v"(whhF[ctl][gate][kf]));

  const float bhN0 = bhh[2*HH + (2*w + 0)*16 + l15];
  const float bhN1 = bhh[2*HH + (2*w + 1)*16 + l15];

  uint32_t* mytag       = (uint32_t*)(ws + (LAYER ? L1TAG_OFF : L0TAG_OFF) + (size_t)g*128);
  const uint32_t* ptag  = (const uint32_t*)(ws + (LAYER ? P1TAG_OFF : P0TAG_OFF)) + g*64;
  const uint32_t* bptag = (const uint32_t*)(ws + P1TAG_OFF) + g*64;
  short* xp  = (short*)(ws + (LAYER ? XP1_OFF : XP0_OFF));
  short* ys  = (short*)(ws + YS_OFF);
  short* fin = (short*)(ws + FIN_OFF);

  __syncthreads();   // pubp zero visible

  wait_nz_cc<1>(ptag);
  int2 xA, xB, xC, xD, xE, xF;
  ISSUE_XP(0);

  float hp[8] = {0,0,0,0,0,0,0,0};

  for (int t = 0; t < SS; ++t) {
    REC_STEP(t)
  }

  // final h frags for out-projection (t=2047 -> buf 1)
  bh8 mf = *(const bh8*)&pubp[4096 + w*512 + l*8];
  short* dst = fin + ((size_t)(LAYER*16 + g)*8 + w)*512 + l*8;
  asm volatile("global_store_dwordx4 %0, %1, off sc0 sc1" :: "v"(dst), "v"(mf) : "memory");
  asm volatile("s_waitcnt vmcnt(0)" ::: "memory");
}

// ---------------- proj0: xp0[t] = x[t]*Wih0^T + bias (K=64) ----------------
__device__ __forceinline__ void run_proj0(const float* __restrict__ x,
                                          uint8_t* __restrict__ ws, int g, int c)
{
  const int tid = threadIdx.x, w = tid >> 6, l = tid & 63, l15 = l & 15, lg = l >> 4;
  if (c >= RING)
    wait_ge_cc<3>((const uint32_t*)(ws + L0TAG_OFF + (size_t)g*128), (uint32_t)(CHS*(c - RING + 1)));
  bh8 A[4][2];
#pragma unroll
  for (int tt = 0; tt < 4; ++tt) {
    const int t = c*32 + w*4 + tt;
#pragma unroll
    for (int kf = 0; kf < 2; ++kf) {
      const float* p = x + ((size_t)t*BB + g*16 + l15)*DD + kf*32 + lg*8;
      A[tt][kf] = cvt8(*(const f4v*)p, *(const f4v*)(p + 4));
    }
  }
  const bh8* WB = (const bh8*)(ws + WBF0_OFF);
  const float* BF = (const float*)(ws + BF0_OFF);
  short* xp0 = (short*)(ws + XP0_OFF);
  const size_t obase = ((size_t)((c & 7)*16 + g)*32 + w*4)*12288 + l*4;
  for (int ct = 0; ct < 48; ++ct) {
    bh8 B0 = WB[(size_t)(ct*2 + 0)*64 + l];
    bh8 B1 = WB[(size_t)(ct*2 + 1)*64 + l];
    const float bb = BF[(ct >> 4)*256 + (ct & 15)*16 + l15];
    const int fid = (ct & 15)*3 + (ct >> 4);
#pragma unroll
    for (int tt = 0; tt < 4; ++tt) {
      fx4 acc = {0.f, 0.f, 0.f, 0.f};
      acc = mfma16(A[tt][0], B0, acc);
      acc = mfma16(A[tt][1], B1, acc);
      int2 v;
      v.x = (int)pack2(acc[0] + bb, acc[1] + bb);
      v.y = (int)pack2(acc[2] + bb, acc[3] + bb);
      short* dst = xp0 + obase + (size_t)tt*12288 + fid*256;
      asm volatile("global_store_dwordx2 %0, %1, off sc0 sc1" :: "v"(dst), "v"(v) : "memory");
    }
  }
  asm volatile("s_waitcnt vmcnt(0)" ::: "memory");
  __syncthreads();
  if (tid == 0) stw_cc((uint32_t*)(ws + P0TAG_OFF) + g*64 + c, 1u);
}

// ---------------- proj1: xp1[t] = ys0[t]*Wih1^T + bias (K=256) --------------
__device__ __forceinline__ void run_proj1(uint8_t* __restrict__ ws, int g, int c)
{
  const int tid = threadIdx.x, w = tid >> 6, l = tid & 63, l15 = l & 15;
  wait_ge_cc<3>((const uint32_t*)(ws + L0TAG_OFF + (size_t)g*128), (uint32_t)(CHS*(c + 1)));
  if (c >= RING)
    wait_ge_cc<3>((const uint32_t*)(ws + L1TAG_OFF + (size_t)g*128), (uint32_t)(CHS*(c - RING + 1)));
  const short* ys = (const short*)(ws + YS_OFF) + ((size_t)((c & 7)*16 + g)*32)*4096;
  bh8 A[4][8];
#pragma unroll
  for (int tt = 0; tt < 4; ++tt)
#pragma unroll
    for (int kf = 0; kf < 8; ++kf)
      A[tt][kf] = gld16_cc(ys + (size_t)(w*4 + tt)*4096 + kf*512 + l*8);
  asm volatile("s_waitcnt vmcnt(0)" ::: "memory");
  __builtin_amdgcn_sched_barrier(0);
  const bh8* WB = (const bh8*)(ws + WBF1_OFF);
  const float* BF = (const float*)(ws + BF1_OFF);
  short* xp1 = (short*)(ws + XP1_OFF);
  const size_t obase = ((size_t)((c & 7)*16 + g)*32 + w*4)*12288 + l*4;
  for (int ct = 0; ct < 48; ++ct) {
    bh8 B[8];
#pragma unroll
    for (int kf = 0; kf < 8; ++kf) B[kf] = WB[(size_t)(ct*8 + kf)*64 + l];
    const float bb = BF[(ct >> 4)*256 + (ct & 15)*16 + l15];
    const int fid = (ct & 15)*3 + (ct >> 4);
#pragma unroll
    for (int tt = 0; tt < 4; ++tt) {
      fx4 acc = {0.f, 0.f, 0.f, 0.f};
#pragma unroll
      for (int kf = 0; kf < 8; ++kf) acc = mfma16(A[tt][kf], B[kf], acc);
      int2 v;
      v.x = (int)pack2(acc[0] + bb, acc[1] + bb);
      v.y = (int)pack2(acc[2] + bb, acc[3] + bb);
      short* dst = xp1 + obase + (size_t)tt*12288 + fid*256;
      asm volatile("global_store_dwordx2 %0, %1, off sc0 sc1" :: "v"(dst), "v"(v) : "memory");
    }
  }
  asm volatile("s_waitcnt vmcnt(0)" ::: "memory");
  __syncthreads();
  if (tid == 0) stw_cc((uint32_t*)(ws + P1TAG_OFF) + g*64 + c, 1u);
}

// ---------------- kernels ----------------
__global__ __launch_bounds__(512) void gru_prep(
    const float* __restrict__ Wih0, const float* __restrict__ Wih1,
    const float* __restrict__ bih0, const float* __restrict__ bhh0,
    const float* __restrict__ bih1, const float* __restrict__ bhh1,
    uint8_t* __restrict__ ws)
{
  const int bid = blockIdx.x, tid = threadIdx.x;
  if (bid == 60) {
    float* BF0 = (float*)(ws + BF0_OFF);
    float* BF1 = (float*)(ws + BF1_OFF);
    for (int i = tid; i < 768; i += 512) {
      const int gate = i >> 8;
      BF0[i] = bih0[i] + (gate < 2 ? bhh0[i] : 0.f);
      BF1[i] = bih1[i] + (gate < 2 ? bhh1[i] : 0.f);
    }
    return;
  }
  const int W = bid*8 + (tid >> 6), l = tid & 63, l15 = l & 15, lg = l >> 4;
  if (W < 96) {
    const int ct = W >> 1, kf = W & 1;
    const float* p = Wih0 + (size_t)(ct*16 + l15)*DD + kf*32 + lg*8;
    ((bh8*)(ws + WBF0_OFF))[(size_t)W*64 + l] = cvt8(*(const f4v*)p, *(const f4v*)(p + 4));
  } else {
    const int V = W - 96, ct = V >> 3, kf = V & 7;
    const float* p = Wih1 + (size_t)(ct*16 + l15)*HH + kf*32 + lg*8;
    ((bh8*)(ws + WBF1_OFF))[(size_t)V*64 + l] = cvt8(*(const f4v*)p, *(const f4v*)(p + 4));
  }
}

__global__ __launch_bounds__(512)
__attribute__((amdgpu_waves_per_eu(2, 2)))
void gru_mega(
    const float* __restrict__ x,
    const float* __restrict__ Whh0, const float* __restrict__ bhh0,
    const float* __restrict__ Whh1, const float* __restrict__ bhh1,
    uint8_t* __restrict__ ws)
{
  __shared__ short pubp[8192];   // [2 buf][8 kf][64 lane][8] h exchange
  const int bid = blockIdx.x;
  if (bid < 16)      run_rec<0>(Whh0, bhh0, ws, bid, pubp);
  else if (bid < 32) run_rec<1>(Whh1, bhh1, ws, bid - 16, pubp);
  else {
    const int j = bid - 32, c = j >> 5, r = j & 31;
    if (r < 16) run_proj0(x, ws, r, c);
    else        run_proj1(ws, r - 16, c);
  }
}

__global__ __launch_bounds__(512) void gru_out(
    const uint8_t* __restrict__ ws,
    const float* __restrict__ Wout, const float* __restrict__ bout,
    float* __restrict__ out)
{
  const short* fin = (const short*)(ws + FIN_OFF);
  const int bid = blockIdx.x;
  const int layer = bid >> 4, g = bid & 15;
  const int tid = threadIdx.x;
  const int row = tid >> 5, o = tid & 31;
  const short* src = fin + (size_t)(layer*16 + g)*4096;
  float acc = 0.f;
#pragma unroll 8
  for (int h = 0; h < HH; ++h) {
    const int f = h >> 5, lane = row + ((h & 31) >> 3)*16, idx = h & 7;
    acc += bf2f(src[f*512 + lane*8 + idx]) * Wout[o*HH + h];
  }
  out[((size_t)(layer*BB) + g*16 + row)*32 + o] = tanh_(acc + bout[o]);
}

extern "C" void kernel_launch(void* const* d_in, const int* in_sizes, int n_in,
                              void* d_out, int out_size, void* d_ws, size_t ws_size,
                              hipStream_t stream) {
  const float* x    = (const float*)d_in[0];
  const float* Wih0 = (const float*)d_in[1];
  const float* Whh0 = (const float*)d_in[2];
  const float* bih0 = (const float*)d_in[3];
  const float* bhh0 = (const float*)d_in[4];
  const float* Wih1 = (const float*)d_in[5];
  const float* Whh1 = (const float*)d_in[6];
  const float* bih1 = (const float*)d_in[7];
  const float* bhh1 = (const float*)d_in[8];
  const float* Wout = (const float*)d_in[9];
  const float* bout = (const float*)d_in[10];
  uint8_t* ws = (uint8_t*)d_ws;

  if (ws_size < WS_NEED) return;

  (void)hipMemsetAsync(ws, 0, 16384, stream);
  gru_prep<<<dim3(61), dim3(512), 0, stream>>>(Wih0, Wih1, bih0, bhh0, bih1, bhh1, ws);
  gru_mega<<<dim3(2080), dim3(512), 0, stream>>>(x, Whh0, bhh0, Whh1, bhh1, ws);
  gru_out<<<dim3(32), dim3(512), 0, stream>>>(ws, Wout, bout, (float*)d_out);
}

// Round 15
// 3597.293 us; speedup vs baseline: 1.8655x; 1.5847x over previous
//
#include <hip/hip_runtime.h>
#include <stdint.h>

#define HH 256
#define SS 2048
#define BB 256
#define DD 64
#define CHS 32
#define RING 8

typedef __attribute__((ext_vector_type(8))) short bh8;
typedef __attribute__((ext_vector_type(4))) float fx4;
typedef __attribute__((ext_vector_type(4))) float f4v;

// ---------------- ws layout (bytes) ----------------
#define L0TAG_OFF 0ull
#define L1TAG_OFF 2048ull
#define P0TAG_OFF 4096ull
#define P1TAG_OFF 8192ull
#define BF0_OFF   12288ull
#define BF1_OFF   16384ull
#define FIN_OFF   20480ull
#define WBF0_OFF  524288ull
#define WBF1_OFF  1048576ull
#define YS_OFF    2097152ull
#define XP0_OFF   37748736ull
#define XP1_OFF   139460608ull
#define WS_NEED   (XP1_OFF + 100663296ull)

__device__ __forceinline__ short f2bf(float f) {
  uint32_t u = __builtin_bit_cast(uint32_t, f);
  u += 0x7FFFu + ((u >> 16) & 1u);
  return (short)(u >> 16);
}
__device__ __forceinline__ float bf2f(short s) {
  uint32_t u = ((uint32_t)(uint16_t)s) << 16;
  return __builtin_bit_cast(float, u);
}
__device__ __forceinline__ float lof(int u) {
  return __builtin_bit_cast(float, (uint32_t)u << 16);
}
__device__ __forceinline__ float hif(int u) {
  return __builtin_bit_cast(float, (uint32_t)u & 0xFFFF0000u);
}
__device__ __forceinline__ uint32_t pack2(float a, float b) {
  return ((uint32_t)(uint16_t)f2bf(a)) | (((uint32_t)(uint16_t)f2bf(b)) << 16);
}
__device__ __forceinline__ float rcp_(float x) { return __builtin_amdgcn_rcpf(x); }
__device__ __forceinline__ float tanh_(float x) {
  x = fminf(fmaxf(x, -15.f), 15.f);
  float e = __expf(2.0f * x);
  return (e - 1.0f) / (e + 1.0f);
}
__device__ __forceinline__ fx4 mfma16(bh8 a, bh8 b, fx4 c) {
  return __builtin_amdgcn_mfma_f32_16x16x32_bf16(a, b, c, 0, 0, 0);
}
__device__ __forceinline__ bh8 cvt8(f4v a, f4v b) {
  bh8 r;
  r[0]=f2bf(a[0]); r[1]=f2bf(a[1]); r[2]=f2bf(a[2]); r[3]=f2bf(a[3]);
  r[4]=f2bf(b[0]); r[5]=f2bf(b[1]); r[6]=f2bf(b[2]); r[7]=f2bf(b[3]);
  return r;
}
__device__ __forceinline__ bh8 gld16_cc(const short* p) {
  bh8 r; asm volatile("global_load_dwordx4 %0, %1, off sc0 sc1" : "=v"(r) : "v"(p));
  return r;
}
__device__ __forceinline__ void stw_cc(uint32_t* p, uint32_t v) {
  asm volatile("global_store_dword %0, %1, off sc0 sc1" :: "v"(p), "v"(v) : "memory");
}
__device__ __forceinline__ void vwait0() {
  asm volatile("s_waitcnt vmcnt(0)" ::: "memory");
  __builtin_amdgcn_sched_barrier(0);
}
__device__ __forceinline__ void vwait1() {
  asm volatile("s_waitcnt vmcnt(1)" ::: "memory");
  __builtin_amdgcn_sched_barrier(0);
}
template<int SLP>
__device__ __forceinline__ void wait_nz_cc(const uint32_t* p) {
  for (;;) {
    uint32_t v;
    asm volatile("global_load_dword %0, %1, off sc0 sc1" : "=v"(v) : "v"(p));
    asm volatile("s_waitcnt vmcnt(0)" ::: "memory");
    if (v != 0u) break;
    __builtin_amdgcn_s_sleep(SLP);
  }
  __builtin_amdgcn_sched_barrier(0);
}
template<int SLP>
__device__ __forceinline__ void wait_ge_cc(const uint32_t* p, uint32_t need) {
  for (;;) {
    uint32_t v;
    asm volatile("global_load_dword %0, %1, off sc0 sc1" : "=v"(v) : "v"(p));
    asm volatile("s_waitcnt vmcnt(0)" ::: "memory");
    if (v >= need) break;
    __builtin_amdgcn_s_sleep(SLP);
  }
  __builtin_amdgcn_sched_barrier(0);
}

// issue 6 xp loads (R,Z,N for 2 col-tiles of wave w) for step T
#define ISSUE_XP(T) \
  { const short* b_ = xp + ((size_t)(((((T) >> 5) & 7))*16 + g)*32 + ((T) & 31))*12288 + w*1536 + l*4; \
    asm volatile("global_load_dwordx2 %0, %1, off sc0 sc1"             : "=v"(xA) : "v"(b_)); \
    asm volatile("global_load_dwordx2 %0, %1, off offset:512 sc0 sc1"  : "=v"(xB) : "v"(b_)); \
    asm volatile("global_load_dwordx2 %0, %1, off offset:1024 sc0 sc1" : "=v"(xC) : "v"(b_)); \
    asm volatile("global_load_dwordx2 %0, %1, off offset:1536 sc0 sc1" : "=v"(xD) : "v"(b_)); \
    asm volatile("global_load_dwordx2 %0, %1, off offset:2048 sc0 sc1" : "=v"(xE) : "v"(b_)); \
    asm volatile("global_load_dwordx2 %0, %1, off offset:2560 sc0 sc1" : "=v"(xF) : "v"(b_)); }

// one column-tile: MFMA over K=256 + gates + publish to LDS
#define CTL_BODY(CTL, PR, PZ, PN, BHN)                                           \
  {                                                                              \
    fx4 accR, accZ, accN;                                                        \
    accR[0]=lof(PR.x); accR[1]=hif(PR.x); accR[2]=lof(PR.y); accR[3]=hif(PR.y);  \
    accZ[0]=lof(PZ.x); accZ[1]=hif(PZ.x); accZ[2]=lof(PZ.y); accZ[3]=hif(PZ.y);  \
    float xn0=lof(PN.x), xn1=hif(PN.x), xn2=lof(PN.y), xn3=hif(PN.y);            \
    accN[0]=0.f; accN[1]=0.f; accN[2]=0.f; accN[3]=0.f;                          \
    _Pragma("unroll")                                                            \
    for (int kf = 0; kf < 8; ++kf) {                                             \
      bh8 a = *(const bh8*)&pubp[rb + kf*512 + l*8];                             \
      accR = mfma16(a, whhF[CTL][0][kf], accR);                                  \
      accZ = mfma16(a, whhF[CTL][1][kf], accZ);                                  \
      accN = mfma16(a, whhF[CTL][2][kf], accN);                                  \
    }                                                                            \
    _Pragma("unroll")                                                            \
    for (int i = 0; i < 4; ++i) {                                                \
      float xnv = (i==0)?xn0:((i==1)?xn1:((i==2)?xn2:xn3));                      \
      float r = rcp_(1.0f + __expf(-accR[i]));                                   \
      float z = rcp_(1.0f + __expf(-accZ[i]));                                   \
      float na = xnv + r * (accN[i] + (BHN));                                    \
      float n = 1.0f - 2.0f * rcp_(__expf(2.0f*na) + 1.0f);                      \
      float h = n + z * (hp[(CTL)*4+i] - n);                                     \
      hp[(CTL)*4+i] = h;                                                         \
      int la = lg*4 + i + 16*((CTL)*2 + b3);                                     \
      pubp[wb + la*8 + j7] = f2bf(h);                                            \
    }                                                                            \
  }

// ---------------- recurrent block: one (layer, 16-row group) per CU ----------
template<int LAYER>
__device__ __forceinline__ void run_rec(
    const float* __restrict__ Whh, const float* __restrict__ bhh,
    uint8_t* __restrict__ ws, int g, short* pubp)
{
  const int tid = threadIdx.x;
  const int w = tid >> 6, l = tid & 63;
  const int l15 = l & 15, lg = l >> 4;
  const int b3 = l15 >> 3, j7 = l & 7;

  for (int i = tid; i < 8192; i += 512) pubp[i] = 0;

  bh8 whhF[2][3][8];
#pragma unroll
  for (int ctl = 0; ctl < 2; ++ctl) {
    const int col = (2*w + ctl)*16 + l15;
#pragma unroll
    for (int gate = 0; gate < 3; ++gate) {
      const float* base = Whh + (size_t)(gate*HH + col)*HH;
#pragma unroll
      for (int kf = 0; kf < 8; ++kf) {
        const float* p = base + kf*32 + lg*8;
        whhF[ctl][gate][kf] = cvt8(*(const f4v*)p, *(const f4v*)(p + 4));
      }
    }
  }
  // pin the 48 weight frags in VGPRs: opaque to rematerialization
#pragma unroll
  for (int ctl = 0; ctl < 2; ++ctl)
#pragma unroll
    for (int gate = 0; gate < 3; ++gate)
#pragma unroll
      for (int kf = 0; kf < 8; ++kf)
        asm volatile("" : "+v"(whhF[ctl][gate][kf]));

  const float bhN0 = bhh[2*HH + (2*w + 0)*16 + l15];
  const float bhN1 = bhh[2*HH + (2*w + 1)*16 + l15];

  uint32_t* mytag       = (uint32_t*)(ws + (LAYER ? L1TAG_OFF : L0TAG_OFF) + (size_t)g*128);
  const uint32_t* ptag  = (const uint32_t*)(ws + (LAYER ? P1TAG_OFF : P0TAG_OFF)) + g*64;
  const uint32_t* bptag = (const uint32_t*)(ws + P1TAG_OFF) + g*64;   // L0 ring bp
  short* xp  = (short*)(ws + (LAYER ? XP1_OFF : XP0_OFF));
  short* ys  = (short*)(ws + YS_OFF);
  short* fin = (short*)(ws + FIN_OFF);

  __syncthreads();

  wait_nz_cc<1>(ptag);
  int2 xA, xB, xC, xD, xE, xF;
  ISSUE_XP(0);
  float hp[8] = {0,0,0,0,0,0,0,0};

  for (int t = 0; t < SS; ++t) {
    const int buf = t & 1;
    const int rb = (buf ^ 1)*4096;       // read prev h frags
    const int wb = buf*4096 + w*512;     // write my frag
    if (LAYER == 0 && (t & (CHS-1)) != 0) vwait1(); else vwait0();

    CTL_BODY(0, xA, xB, xC, bhN0)
    CTL_BODY(1, xD, xE, xF, bhN1)

    const int tn = t + 1;
    if (tn < SS) {
      if ((tn & (CHS-1)) == 0) {
        wait_nz_cc<2>(ptag + (tn >> 5));
        if (LAYER == 0 && (tn >> 5) >= RING) wait_nz_cc<2>(bptag + ((tn >> 5) - RING));
      }
      ISSUE_XP(tn);
    }
    if (LAYER == 0) {
      bh8 mf = *(const bh8*)&pubp[buf*4096 + w*512 + l*8];
      short* dst = ys + ((size_t)(((t >> 5) & 7)*16 + g)*32 + (t & 31))*4096 + w*512 + l*8;
      asm volatile("global_store_dwordx4 %0, %1, off sc0 sc1" :: "v"(dst), "v"(mf) : "memory");
    }
    __syncthreads();
    if ((tn & (CHS-1)) == 0) {
      asm volatile("s_waitcnt vmcnt(0)" ::: "memory");
      __syncthreads();
      if (tid == 0) stw_cc(mytag, (uint32_t)tn);
    }
  }
  // final h frags for out-projection
  bh8 mf = *(const bh8*)&pubp[4096 + w*512 + l*8];   // buf of t=2047 is 1
  short* dst = fin + ((size_t)(LAYER*16 + g)*8 + w)*512 + l*8;
  asm volatile("global_store_dwordx4 %0, %1, off sc0 sc1" :: "v"(dst), "v"(mf) : "memory");
  asm volatile("s_waitcnt vmcnt(0)" ::: "memory");
}

// ---------------- proj0: xp0[t] = x[t]*Wih0^T + bias (K=64) ----------------
__device__ __forceinline__ void run_proj0(const float* __restrict__ x,
                                          uint8_t* __restrict__ ws, int g, int c)
{
  const int tid = threadIdx.x, w = tid >> 6, l = tid & 63, l15 = l & 15, lg = l >> 4;
  if (c >= RING)
    wait_ge_cc<3>((const uint32_t*)(ws + L0TAG_OFF + (size_t)g*128), (uint32_t)(CHS*(c - RING + 1)));
  bh8 A[4][2];
#pragma unroll
  for (int tt = 0; tt < 4; ++tt) {
    const int t = c*32 + w*4 + tt;
#pragma unroll
    for (int kf = 0; kf < 2; ++kf) {
      const float* p = x + ((size_t)t*BB + g*16 + l15)*DD + kf*32 + lg*8;
      A[tt][kf] = cvt8(*(const f4v*)p, *(const f4v*)(p + 4));
    }
  }
  const bh8* WB = (const bh8*)(ws + WBF0_OFF);
  const float* BF = (const float*)(ws + BF0_OFF);
  short* xp0 = (short*)(ws + XP0_OFF);
  const size_t obase = ((size_t)((c & 7)*16 + g)*32 + w*4)*12288 + l*4;
  for (int ct = 0; ct < 48; ++ct) {
    bh8 B0 = WB[(size_t)(ct*2 + 0)*64 + l];
    bh8 B1 = WB[(size_t)(ct*2 + 1)*64 + l];
    const float bb = BF[(ct >> 4)*256 + (ct & 15)*16 + l15];
    const int fid = (ct & 15)*3 + (ct >> 4);
#pragma unroll
    for (int tt = 0; tt < 4; ++tt) {
      fx4 acc = {0.f, 0.f, 0.f, 0.f};
      acc = mfma16(A[tt][0], B0, acc);
      acc = mfma16(A[tt][1], B1, acc);
      int2 v;
      v.x = (int)pack2(acc[0] + bb, acc[1] + bb);
      v.y = (int)pack2(acc[2] + bb, acc[3] + bb);
      short* dst = xp0 + obase + (size_t)tt*12288 + fid*256;
      asm volatile("global_store_dwordx2 %0, %1, off sc0 sc1" :: "v"(dst), "v"(v) : "memory");
    }
  }
  asm volatile("s_waitcnt vmcnt(0)" ::: "memory");
  __syncthreads();
  if (tid == 0) stw_cc((uint32_t*)(ws + P0TAG_OFF) + g*64 + c, 1u);
}

// ---------------- proj1: xp1[t] = ys0[t]*Wih1^T + bias (K=256) --------------
__device__ __forceinline__ void run_proj1(uint8_t* __restrict__ ws, int g, int c)
{
  const int tid = threadIdx.x, w = tid >> 6, l = tid & 63, l15 = l & 15;
  wait_ge_cc<3>((const uint32_t*)(ws + L0TAG_OFF + (size_t)g*128), (uint32_t)(CHS*(c + 1)));
  if (c >= RING)
    wait_ge_cc<3>((const uint32_t*)(ws + L1TAG_OFF + (size_t)g*128), (uint32_t)(CHS*(c - RING + 1)));
  const short* ys = (const short*)(ws + YS_OFF) + ((size_t)((c & 7)*16 + g)*32)*4096;
  bh8 A[4][8];
#pragma unroll
  for (int tt = 0; tt < 4; ++tt)
#pragma unroll
    for (int kf = 0; kf < 8; ++kf)
      A[tt][kf] = gld16_cc(ys + (size_t)(w*4 + tt)*4096 + kf*512 + l*8);
  asm volatile("s_waitcnt vmcnt(0)" ::: "memory");
  __builtin_amdgcn_sched_barrier(0);
  const bh8* WB = (const bh8*)(ws + WBF1_OFF);
  const float* BF = (const float*)(ws + BF1_OFF);
  short* xp1 = (short*)(ws + XP1_OFF);
  const size_t obase = ((size_t)((c & 7)*16 + g)*32 + w*4)*12288 + l*4;
  for (int ct = 0; ct < 48; ++ct) {
    bh8 B[8];
#pragma unroll
    for (int kf = 0; kf < 8; ++kf) B[kf] = WB[(size_t)(ct*8 + kf)*64 + l];
    const float bb = BF[(ct >> 4)*256 + (ct & 15)*16 + l15];
    const int fid = (ct & 15)*3 + (ct >> 4);
#pragma unroll
    for (int tt = 0; tt < 4; ++tt) {
      fx4 acc = {0.f, 0.f, 0.f, 0.f};
#pragma unroll
      for (int kf = 0; kf < 8; ++kf) acc = mfma16(A[tt][kf], B[kf], acc);
      int2 v;
      v.x = (int)pack2(acc[0] + bb, acc[1] + bb);
      v.y = (int)pack2(acc[2] + bb, acc[3] + bb);
      short* dst = xp1 + obase + (size_t)tt*12288 + fid*256;
      asm volatile("global_store_dwordx2 %0, %1, off sc0 sc1" :: "v"(dst), "v"(v) : "memory");
    }
  }
  asm volatile("s_waitcnt vmcnt(0)" ::: "memory");
  __syncthreads();
  if (tid == 0) stw_cc((uint32_t*)(ws + P1TAG_OFF) + g*64 + c, 1u);
}

// ---------------- kernels ----------------
__global__ __launch_bounds__(512) void gru_prep(
    const float* __restrict__ Wih0, const float* __restrict__ Wih1,
    const float* __restrict__ bih0, const float* __restrict__ bhh0,
    const float* __restrict__ bih1, const float* __restrict__ bhh1,
    uint8_t* __restrict__ ws)
{
  const int bid = blockIdx.x, tid = threadIdx.x;
  if (bid == 60) {
    float* BF0 = (float*)(ws + BF0_OFF);
    float* BF1 = (float*)(ws + BF1_OFF);
    for (int i = tid; i < 768; i += 512) {
      const int gate = i >> 8;
      BF0[i] = bih0[i] + (gate < 2 ? bhh0[i] : 0.f);
      BF1[i] = bih1[i] + (gate < 2 ? bhh1[i] : 0.f);
    }
    return;
  }
  const int W = bid*8 + (tid >> 6), l = tid & 63, l15 = l & 15, lg = l >> 4;
  if (W < 96) {
    const int ct = W >> 1, kf = W & 1;
    const float* p = Wih0 + (size_t)(ct*16 + l15)*DD + kf*32 + lg*8;
    ((bh8*)(ws + WBF0_OFF))[(size_t)W*64 + l] = cvt8(*(const f4v*)p, *(const f4v*)(p + 4));
  } else {
    const int V = W - 96, ct = V >> 3, kf = V & 7;
    const float* p = Wih1 + (size_t)(ct*16 + l15)*HH + kf*32 + lg*8;
    ((bh8*)(ws + WBF1_OFF))[(size_t)V*64 + l] = cvt8(*(const f4v*)p, *(const f4v*)(p + 4));
  }
}

__global__ __launch_bounds__(512)
__attribute__((amdgpu_waves_per_eu(2, 2)))
void gru_mega(
    const float* __restrict__ x,
    const float* __restrict__ Whh0, const float* __restrict__ bhh0,
    const float* __restrict__ Whh1, const float* __restrict__ bhh1,
    uint8_t* __restrict__ ws)
{
  __shared__ short pubp[8192];   // [2 buf][8 kf][64 lane][8] h exchange
  const int bid = blockIdx.x;
  if (bid < 16)      run_rec<0>(Whh0, bhh0, ws, bid, pubp);
  else if (bid < 32) run_rec<1>(Whh1, bhh1, ws, bid - 16, pubp);
  else {
    const int j = bid - 32, c = j >> 5, r = j & 31;
    if (r < 16) run_proj0(x, ws, r, c);
    else        run_proj1(ws, r - 16, c);
  }
}

__global__ __launch_bounds__(512) void gru_out(
    const uint8_t* __restrict__ ws,
    const float* __restrict__ Wout, const float* __restrict__ bout,
    float* __restrict__ out)
{
  const short* fin = (const short*)(ws + FIN_OFF);
  const int bid = blockIdx.x;
  const int layer = bid >> 4, g = bid & 15;
  const int tid = threadIdx.x;
  const int row = tid >> 5, o = tid & 31;
  const short* src = fin + (size_t)(layer*16 + g)*4096;
  float acc = 0.f;
#pragma unroll 8
  for (int h = 0; h < HH; ++h) {
    const int f = h >> 5, lane = row + ((h & 31) >> 3)*16, idx = h & 7;
    acc += bf2f(src[f*512 + lane*8 + idx]) * Wout[o*HH + h];
  }
  out[((size_t)(layer*BB) + g*16 + row)*32 + o] = tanh_(acc + bout[o]);
}

extern "C" void kernel_launch(void* const* d_in, const int* in_sizes, int n_in,
                              void* d_out, int out_size, void* d_ws, size_t ws_size,
                              hipStream_t stream) {
  const float* x    = (const float*)d_in[0];
  const float* Wih0 = (const float*)d_in[1];
  const float* Whh0 = (const float*)d_in[2];
  const float* bih0 = (const float*)d_in[3];
  const float* bhh0 = (const float*)d_in[4];
  const float* Wih1 = (const float*)d_in[5];
  const float* Whh1 = (const float*)d_in[6];
  const float* bih1 = (const float*)d_in[7];
  const float* bhh1 = (const float*)d_in[8];
  const float* Wout = (const float*)d_in[9];
  const float* bout = (const float*)d_in[10];
  uint8_t* ws = (uint8_t*)d_ws;

  if (ws_size < WS_NEED) return;   // ~229MB of scratch

  (void)hipMemsetAsync(ws, 0, 16384, stream);   // all tag arrays
  gru_prep<<<dim3(61), dim3(512), 0, stream>>>(Wih0, Wih1, bih0, bhh0, bih1, bhh1, ws);
  gru_mega<<<dim3(2080), dim3(512), 0, stream>>>(x, Whh0, bhh0, Whh1, bhh1, ws);
  gru_out<<<dim3(32), dim3(512), 0, stream>>>(ws, Wout, bout, (float*)d_out);
}

// Round 16
// 3577.777 us; speedup vs baseline: 1.8757x; 1.0055x over previous
//
#include <hip/hip_runtime.h>
#include <stdint.h>

#define HH 256
#define SS 2048
#define BB 256
#define DD 64
#define CHS 32
#define RING 4   // ring depth: 4 slots -> xp rings 100MB total, MALL-resident

typedef __attribute__((ext_vector_type(8))) short bh8;
typedef __attribute__((ext_vector_type(4))) float fx4;
typedef __attribute__((ext_vector_type(4))) float f4v;

// ---------------- ws layout (bytes) ----------------
#define L0TAG_OFF 0ull
#define L1TAG_OFF 2048ull
#define P0TAG_OFF 4096ull
#define P1TAG_OFF 8192ull
#define BF0_OFF   12288ull
#define BF1_OFF   16384ull
#define FIN_OFF   20480ull
#define WBF0_OFF  524288ull
#define WBF1_OFF  1048576ull
#define YS_OFF    2097152ull
#define XP0_OFF   37748736ull
#define XP1_OFF   139460608ull
#define WS_NEED   (XP1_OFF + 100663296ull)

__device__ __forceinline__ short f2bf(float f) {
  uint32_t u = __builtin_bit_cast(uint32_t, f);
  u += 0x7FFFu + ((u >> 16) & 1u);
  return (short)(u >> 16);
}
__device__ __forceinline__ float bf2f(short s) {
  uint32_t u = ((uint32_t)(uint16_t)s) << 16;
  return __builtin_bit_cast(float, u);
}
__device__ __forceinline__ float lof(int u) {
  return __builtin_bit_cast(float, (uint32_t)u << 16);
}
__device__ __forceinline__ float hif(int u) {
  return __builtin_bit_cast(float, (uint32_t)u & 0xFFFF0000u);
}
__device__ __forceinline__ uint32_t pack2(float a, float b) {
  return ((uint32_t)(uint16_t)f2bf(a)) | (((uint32_t)(uint16_t)f2bf(b)) << 16);
}
__device__ __forceinline__ float rcp_(float x) { return __builtin_amdgcn_rcpf(x); }
__device__ __forceinline__ float tanh_(float x) {
  x = fminf(fmaxf(x, -15.f), 15.f);
  float e = __expf(2.0f * x);
  return (e - 1.0f) / (e + 1.0f);
}
__device__ __forceinline__ fx4 mfma16(bh8 a, bh8 b, fx4 c) {
  return __builtin_amdgcn_mfma_f32_16x16x32_bf16(a, b, c, 0, 0, 0);
}
__device__ __forceinline__ bh8 cvt8(f4v a, f4v b) {
  bh8 r;
  r[0]=f2bf(a[0]); r[1]=f2bf(a[1]); r[2]=f2bf(a[2]); r[3]=f2bf(a[3]);
  r[4]=f2bf(b[0]); r[5]=f2bf(b[1]); r[6]=f2bf(b[2]); r[7]=f2bf(b[3]);
  return r;
}
__device__ __forceinline__ bh8 gld16_cc(const short* p) {
  bh8 r; asm volatile("global_load_dwordx4 %0, %1, off sc0 sc1" : "=v"(r) : "v"(p));
  return r;
}
__device__ __forceinline__ void stw_cc(uint32_t* p, uint32_t v) {
  asm volatile("global_store_dword %0, %1, off sc0 sc1" :: "v"(p), "v"(v) : "memory");
}
__device__ __forceinline__ void vwait0() {
  asm volatile("s_waitcnt vmcnt(0)" ::: "memory");
  __builtin_amdgcn_sched_barrier(0);
}
__device__ __forceinline__ void vwait1() {
  asm volatile("s_waitcnt vmcnt(1)" ::: "memory");
  __builtin_amdgcn_sched_barrier(0);
}
template<int SLP>
__device__ __forceinline__ void wait_nz_cc(const uint32_t* p) {
  for (;;) {
    uint32_t v;
    asm volatile("global_load_dword %0, %1, off sc0 sc1" : "=v"(v) : "v"(p));
    asm volatile("s_waitcnt vmcnt(0)" ::: "memory");
    if (v != 0u) break;
    __builtin_amdgcn_s_sleep(SLP);
  }
  __builtin_amdgcn_sched_barrier(0);
}
template<int SLP>
__device__ __forceinline__ void wait_ge_cc(const uint32_t* p, uint32_t need) {
  for (;;) {
    uint32_t v;
    asm volatile("global_load_dword %0, %1, off sc0 sc1" : "=v"(v) : "v"(p));
    asm volatile("s_waitcnt vmcnt(0)" ::: "memory");
    if (v >= need) break;
    __builtin_amdgcn_s_sleep(SLP);
  }
  __builtin_amdgcn_sched_barrier(0);
}

// issue 6 xp loads (R,Z,N for 2 col-tiles of wave w) for step T
#define ISSUE_XP(T) \
  { const short* b_ = xp + ((size_t)(((((T) >> 5) & (RING-1)))*16 + g)*32 + ((T) & 31))*12288 + w*1536 + l*4; \
    asm volatile("global_load_dwordx2 %0, %1, off sc0 sc1"             : "=v"(xA) : "v"(b_)); \
    asm volatile("global_load_dwordx2 %0, %1, off offset:512 sc0 sc1"  : "=v"(xB) : "v"(b_)); \
    asm volatile("global_load_dwordx2 %0, %1, off offset:1024 sc0 sc1" : "=v"(xC) : "v"(b_)); \
    asm volatile("global_load_dwordx2 %0, %1, off offset:1536 sc0 sc1" : "=v"(xD) : "v"(b_)); \
    asm volatile("global_load_dwordx2 %0, %1, off offset:2048 sc0 sc1" : "=v"(xE) : "v"(b_)); \
    asm volatile("global_load_dwordx2 %0, %1, off offset:2560 sc0 sc1" : "=v"(xF) : "v"(b_)); }

// one column-tile: MFMA over K=256 + gates + publish to LDS
#define CTL_BODY(CTL, PR, PZ, PN, BHN)                                           \
  {                                                                              \
    fx4 accR, accZ, accN;                                                        \
    accR[0]=lof(PR.x); accR[1]=hif(PR.x); accR[2]=lof(PR.y); accR[3]=hif(PR.y);  \
    accZ[0]=lof(PZ.x); accZ[1]=hif(PZ.x); accZ[2]=lof(PZ.y); accZ[3]=hif(PZ.y);  \
    float xn0=lof(PN.x), xn1=hif(PN.x), xn2=lof(PN.y), xn3=hif(PN.y);            \
    accN[0]=0.f; accN[1]=0.f; accN[2]=0.f; accN[3]=0.f;                          \
    _Pragma("unroll")                                                            \
    for (int kf = 0; kf < 8; ++kf) {                                             \
      bh8 a = *(const bh8*)&pubp[rb + kf*512 + l*8];                             \
      accR = mfma16(a, whhF[CTL][0][kf], accR);                                  \
      accZ = mfma16(a, whhF[CTL][1][kf], accZ);                                  \
      accN = mfma16(a, whhF[CTL][2][kf], accN);                                  \
    }                                                                            \
    _Pragma("unroll")                                                            \
    for (int i = 0; i < 4; ++i) {                                                \
      float xnv = (i==0)?xn0:((i==1)?xn1:((i==2)?xn2:xn3));                      \
      float r = rcp_(1.0f + __expf(-accR[i]));                                   \
      float z = rcp_(1.0f + __expf(-accZ[i]));                                   \
      float na = xnv + r * (accN[i] + (BHN));                                    \
      float n = 1.0f - 2.0f * rcp_(__expf(2.0f*na) + 1.0f);                      \
      float h = n + z * (hp[(CTL)*4+i] - n);                                     \
      hp[(CTL)*4+i] = h;                                                         \
      int la = lg*4 + i + 16*((CTL)*2 + b3);                                     \
      pubp[wb + la*8 + j7] = f2bf(h);                                            \
    }                                                                            \
  }

// ---------------- recurrent block: one (layer, 16-row group) per CU ----------
template<int LAYER>
__device__ __forceinline__ void run_rec(
    const float* __restrict__ Whh, const float* __restrict__ bhh,
    uint8_t* __restrict__ ws, int g, short* pubp)
{
  const int tid = threadIdx.x;
  const int w = tid >> 6, l = tid & 63;
  const int l15 = l & 15, lg = l >> 4;
  const int b3 = l15 >> 3, j7 = l & 7;

  for (int i = tid; i < 8192; i += 512) pubp[i] = 0;

  bh8 whhF[2][3][8];
#pragma unroll
  for (int ctl = 0; ctl < 2; ++ctl) {
    const int col = (2*w + ctl)*16 + l15;
#pragma unroll
    for (int gate = 0; gate < 3; ++gate) {
      const float* base = Whh + (size_t)(gate*HH + col)*HH;
#pragma unroll
      for (int kf = 0; kf < 8; ++kf) {
        const float* p = base + kf*32 + lg*8;
        whhF[ctl][gate][kf] = cvt8(*(const f4v*)p, *(const f4v*)(p + 4));
      }
    }
  }
  // pin the 48 weight frags in VGPRs: opaque to rematerialization
#pragma unroll
  for (int ctl = 0; ctl < 2; ++ctl)
#pragma unroll
    for (int gate = 0; gate < 3; ++gate)
#pragma unroll
      for (int kf = 0; kf < 8; ++kf)
        asm volatile("" : "+v"(whhF[ctl][gate][kf]));

  const float bhN0 = bhh[2*HH + (2*w + 0)*16 + l15];
  const float bhN1 = bhh[2*HH + (2*w + 1)*16 + l15];

  uint32_t* mytag       = (uint32_t*)(ws + (LAYER ? L1TAG_OFF : L0TAG_OFF) + (size_t)g*128);
  const uint32_t* ptag  = (const uint32_t*)(ws + (LAYER ? P1TAG_OFF : P0TAG_OFF)) + g*64;
  const uint32_t* bptag = (const uint32_t*)(ws + P1TAG_OFF) + g*64;   // L0 ring bp
  short* xp  = (short*)(ws + (LAYER ? XP1_OFF : XP0_OFF));
  short* ys  = (short*)(ws + YS_OFF);
  short* fin = (short*)(ws + FIN_OFF);

  __syncthreads();

  wait_nz_cc<1>(ptag);
  int2 xA, xB, xC, xD, xE, xF;
  ISSUE_XP(0);
  float hp[8] = {0,0,0,0,0,0,0,0};

  for (int t = 0; t < SS; ++t) {
    const int buf = t & 1;
    const int rb = (buf ^ 1)*4096;       // read prev h frags
    const int wb = buf*4096 + w*512;     // write my frag
    if (LAYER == 0 && (t & (CHS-1)) != 0) vwait1(); else vwait0();

    CTL_BODY(0, xA, xB, xC, bhN0)
    CTL_BODY(1, xD, xE, xF, bhN1)

    const int tn = t + 1;
    if (tn < SS) {
      if ((tn & (CHS-1)) == 0) {
        wait_nz_cc<2>(ptag + (tn >> 5));
        if (LAYER == 0 && (tn >> 5) >= RING) wait_nz_cc<2>(bptag + ((tn >> 5) - RING));
      }
      ISSUE_XP(tn);
    }
    if (LAYER == 0) {
      bh8 mf = *(const bh8*)&pubp[buf*4096 + w*512 + l*8];
      short* dst = ys + ((size_t)(((t >> 5) & (RING-1))*16 + g)*32 + (t & 31))*4096 + w*512 + l*8;
      asm volatile("global_store_dwordx4 %0, %1, off sc0 sc1" :: "v"(dst), "v"(mf) : "memory");
    }
    __syncthreads();
    if ((tn & (CHS-1)) == 0) {
      asm volatile("s_waitcnt vmcnt(0)" ::: "memory");
      __syncthreads();
      if (tid == 0) stw_cc(mytag, (uint32_t)tn);
    }
  }
  // final h frags for out-projection
  bh8 mf = *(const bh8*)&pubp[4096 + w*512 + l*8];   // buf of t=2047 is 1
  short* dst = fin + ((size_t)(LAYER*16 + g)*8 + w)*512 + l*8;
  asm volatile("global_store_dwordx4 %0, %1, off sc0 sc1" :: "v"(dst), "v"(mf) : "memory");
  asm volatile("s_waitcnt vmcnt(0)" ::: "memory");
}

// ---------------- proj0: xp0[t] = x[t]*Wih0^T + bias (K=64) ----------------
__device__ __forceinline__ void run_proj0(const float* __restrict__ x,
                                          uint8_t* __restrict__ ws, int g, int c)
{
  const int tid = threadIdx.x, w = tid >> 6, l = tid & 63, l15 = l & 15, lg = l >> 4;
  if (c >= RING)
    wait_ge_cc<3>((const uint32_t*)(ws + L0TAG_OFF + (size_t)g*128), (uint32_t)(CHS*(c - RING + 1)));
  bh8 A[4][2];
#pragma unroll
  for (int tt = 0; tt < 4; ++tt) {
    const int t = c*32 + w*4 + tt;
#pragma unroll
    for (int kf = 0; kf < 2; ++kf) {
      const float* p = x + ((size_t)t*BB + g*16 + l15)*DD + kf*32 + lg*8;
      A[tt][kf] = cvt8(*(const f4v*)p, *(const f4v*)(p + 4));
    }
  }
  const bh8* WB = (const bh8*)(ws + WBF0_OFF);
  const float* BF = (const float*)(ws + BF0_OFF);
  short* xp0 = (short*)(ws + XP0_OFF);
  const size_t obase = ((size_t)((c & (RING-1))*16 + g)*32 + w*4)*12288 + l*4;
  for (int ct = 0; ct < 48; ++ct) {
    bh8 B0 = WB[(size_t)(ct*2 + 0)*64 + l];
    bh8 B1 = WB[(size_t)(ct*2 + 1)*64 + l];
    const float bb = BF[(ct >> 4)*256 + (ct & 15)*16 + l15];
    const int fid = (ct & 15)*3 + (ct >> 4);
#pragma unroll
    for (int tt = 0; tt < 4; ++tt) {
      fx4 acc = {0.f, 0.f, 0.f, 0.f};
      acc = mfma16(A[tt][0], B0, acc);
      acc = mfma16(A[tt][1], B1, acc);
      int2 v;
      v.x = (int)pack2(acc[0] + bb, acc[1] + bb);
      v.y = (int)pack2(acc[2] + bb, acc[3] + bb);
      short* dst = xp0 + obase + (size_t)tt*12288 + fid*256;
      asm volatile("global_store_dwordx2 %0, %1, off sc0 sc1" :: "v"(dst), "v"(v) : "memory");
    }
  }
  asm volatile("s_waitcnt vmcnt(0)" ::: "memory");
  __syncthreads();
  if (tid == 0) stw_cc((uint32_t*)(ws + P0TAG_OFF) + g*64 + c, 1u);
}

// ---------------- proj1: xp1[t] = ys0[t]*Wih1^T + bias (K=256) --------------
__device__ __forceinline__ void run_proj1(uint8_t* __restrict__ ws, int g, int c)
{
  const int tid = threadIdx.x, w = tid >> 6, l = tid & 63, l15 = l & 15;
  wait_ge_cc<3>((const uint32_t*)(ws + L0TAG_OFF + (size_t)g*128), (uint32_t)(CHS*(c + 1)));
  if (c >= RING)
    wait_ge_cc<3>((const uint32_t*)(ws + L1TAG_OFF + (size_t)g*128), (uint32_t)(CHS*(c - RING + 1)));
  const short* ys = (const short*)(ws + YS_OFF) + ((size_t)((c & (RING-1))*16 + g)*32)*4096;
  bh8 A[4][8];
#pragma unroll
  for (int tt = 0; tt < 4; ++tt)
#pragma unroll
    for (int kf = 0; kf < 8; ++kf)
      A[tt][kf] = gld16_cc(ys + (size_t)(w*4 + tt)*4096 + kf*512 + l*8);
  asm volatile("s_waitcnt vmcnt(0)" ::: "memory");
  __builtin_amdgcn_sched_barrier(0);
  const bh8* WB = (const bh8*)(ws + WBF1_OFF);
  const float* BF = (const float*)(ws + BF1_OFF);
  short* xp1 = (short*)(ws + XP1_OFF);
  const size_t obase = ((size_t)((c & (RING-1))*16 + g)*32 + w*4)*12288 + l*4;
  for (int ct = 0; ct < 48; ++ct) {
    bh8 B[8];
#pragma unroll
    for (int kf = 0; kf < 8; ++kf) B[kf] = WB[(size_t)(ct*8 + kf)*64 + l];
    const float bb = BF[(ct >> 4)*256 + (ct & 15)*16 + l15];
    const int fid = (ct & 15)*3 + (ct >> 4);
#pragma unroll
    for (int tt = 0; tt < 4; ++tt) {
      fx4 acc = {0.f, 0.f, 0.f, 0.f};
#pragma unroll
      for (int kf = 0; kf < 8; ++kf) acc = mfma16(A[tt][kf], B[kf], acc);
      int2 v;
      v.x = (int)pack2(acc[0] + bb, acc[1] + bb);
      v.y = (int)pack2(acc[2] + bb, acc[3] + bb);
      short* dst = xp1 + obase + (size_t)tt*12288 + fid*256;
      asm volatile("global_store_dwordx2 %0, %1, off sc0 sc1" :: "v"(dst), "v"(v) : "memory");
    }
  }
  asm volatile("s_waitcnt vmcnt(0)" ::: "memory");
  __syncthreads();
  if (tid == 0) stw_cc((uint32_t*)(ws + P1TAG_OFF) + g*64 + c, 1u);
}

// ---------------- kernels ----------------
__global__ __launch_bounds__(512) void gru_prep(
    const float* __restrict__ Wih0, const float* __restrict__ Wih1,
    const float* __restrict__ bih0, const float* __restrict__ bhh0,
    const float* __restrict__ bih1, const float* __restrict__ bhh1,
    uint8_t* __restrict__ ws)
{
  const int bid = blockIdx.x, tid = threadIdx.x;
  if (bid == 60) {
    float* BF0 = (float*)(ws + BF0_OFF);
    float* BF1 = (float*)(ws + BF1_OFF);
    for (int i = tid; i < 768; i += 512) {
      const int gate = i >> 8;
      BF0[i] = bih0[i] + (gate < 2 ? bhh0[i] : 0.f);
      BF1[i] = bih1[i] + (gate < 2 ? bhh1[i] : 0.f);
    }
    return;
  }
  const int W = bid*8 + (tid >> 6), l = tid & 63, l15 = l & 15, lg = l >> 4;
  if (W < 96) {
    const int ct = W >> 1, kf = W & 1;
    const float* p = Wih0 + (size_t)(ct*16 + l15)*DD + kf*32 + lg*8;
    ((bh8*)(ws + WBF0_OFF))[(size_t)W*64 + l] = cvt8(*(const f4v*)p, *(const f4v*)(p + 4));
  } else {
    const int V = W - 96, ct = V >> 3, kf = V & 7;
    const float* p = Wih1 + (size_t)(ct*16 + l15)*HH + kf*32 + lg*8;
    ((bh8*)(ws + WBF1_OFF))[(size_t)V*64 + l] = cvt8(*(const f4v*)p, *(const f4v*)(p + 4));
  }
}

__global__ __launch_bounds__(512)
__attribute__((amdgpu_waves_per_eu(2, 2)))
void gru_mega(
    const float* __restrict__ x,
    const float* __restrict__ Whh0, const float* __restrict__ bhh0,
    const float* __restrict__ Whh1, const float* __restrict__ bhh1,
    uint8_t* __restrict__ ws)
{
  __shared__ short pubp[8192];   // [2 buf][8 kf][64 lane][8] h exchange
  const int bid = blockIdx.x;
  if (bid < 16)      run_rec<0>(Whh0, bhh0, ws, bid, pubp);
  else if (bid < 32) run_rec<1>(Whh1, bhh1, ws, bid - 16, pubp);
  else {
    const int j = bid - 32, c = j >> 5, r = j & 31;
    if (r < 16) run_proj0(x, ws, r, c);
    else        run_proj1(ws, r - 16, c);
  }
}

__global__ __launch_bounds__(512) void gru_out(
    const uint8_t* __restrict__ ws,
    const float* __restrict__ Wout, const float* __restrict__ bout,
    float* __restrict__ out)
{
  const short* fin = (const short*)(ws + FIN_OFF);
  const int bid = blockIdx.x;
  const int layer = bid >> 4, g = bid & 15;
  const int tid = threadIdx.x;
  const int row = tid >> 5, o = tid & 31;
  const short* src = fin + (size_t)(layer*16 + g)*4096;
  float acc = 0.f;
#pragma unroll 8
  for (int h = 0; h < HH; ++h) {
    const int f = h >> 5, lane = row + ((h & 31) >> 3)*16, idx = h & 7;
    acc += bf2f(src[f*512 + lane*8 + idx]) * Wout[o*HH + h];
  }
  out[((size_t)(layer*BB) + g*16 + row)*32 + o] = tanh_(acc + bout[o]);
}

extern "C" void kernel_launch(void* const* d_in, const int* in_sizes, int n_in,
                              void* d_out, int out_size, void* d_ws, size_t ws_size,
                              hipStream_t stream) {
  const float* x    = (const float*)d_in[0];
  const float* Wih0 = (const float*)d_in[1];
  const float* Whh0 = (const float*)d_in[2];
  const float* bih0 = (const float*)d_in[3];
  const float* bhh0 = (const float*)d_in[4];
  const float* Wih1 = (const float*)d_in[5];
  const float* Whh1 = (const float*)d_in[6];
  const float* bih1 = (const float*)d_in[7];
  const float* bhh1 = (const float*)d_in[8];
  const float* Wout = (const float*)d_in[9];
  const float* bout = (const float*)d_in[10];
  uint8_t* ws = (uint8_t*)d_ws;

  if (ws_size < WS_NEED) return;   // ~229MB of scratch (RING=4 uses less)

  (void)hipMemsetAsync(ws, 0, 16384, stream);   // all tag arrays
  gru_prep<<<dim3(61), dim3(512), 0, stream>>>(Wih0, Wih1, bih0, bhh0, bih1, bhh1, ws);
  gru_mega<<<dim3(2080), dim3(512), 0, stream>>>(x, Whh0, bhh0, Whh1, bhh1, ws);
  gru_out<<<dim3(32), dim3(512), 0, stream>>>(ws, Wout, bout, (float*)d_out);
}